// Round 1
// baseline (423.234 us; speedup 1.0000x reference)
//
#include <hip/hip_runtime.h>
#include <hip/hip_bf16.h>

typedef __bf16 bf16;
typedef __bf16 bf16x8 __attribute__((ext_vector_type(8)));
typedef float f32x4 __attribute__((ext_vector_type(4)));

constexpr int B = 4, S = 2048, E = 1024, H = 16, HD = 64;

// ---------------------------------------------------------------------------
// Kernel 1: per-head QKV projections (fp32 VALU), emit bf16.
//   Q: [B,H,S,64] (pre-scaled by 1/sqrt(64)=0.125)
//   K: [B,H,S,64]
//   V: [B,H,64,S]  (transposed so attention PV B-frags are contiguous)
// Block: 256 thr, handles 64 tokens of one (b,h). lane = token, wave owns 16 e's.
// ---------------------------------------------------------------------------
__global__ __launch_bounds__(256) void qkv_proj(
    const float* __restrict__ xq, const float* __restrict__ xk, const float* __restrict__ xv,
    const float* __restrict__ Wq, const float* __restrict__ bq,
    const float* __restrict__ Wk, const float* __restrict__ bk,
    const float* __restrict__ Wv, const float* __restrict__ bv,
    bf16* __restrict__ Qb, bf16* __restrict__ Kb, bf16* __restrict__ Vt)
{
    const int b = blockIdx.z, h = blockIdx.y, s0 = blockIdx.x * 64;
    const int tid = threadIdx.x;
    const int lane = tid & 63;
    const int w16 = __builtin_amdgcn_readfirstlane((tid >> 6) * 16); // e-offset of wave

    __shared__ float xs[64][65];   // [token][d], pad 65 -> conflict-free scalar reads
    __shared__ float ts[64][65];   // transpose-staging for coalesced bf16 output

    const size_t bh = (size_t)b * H + h;

    for (int p = 0; p < 3; ++p) {
        const float* x    = (p == 0) ? xq : (p == 1) ? xk : xv;
        const float* W    = (p == 0) ? Wq : (p == 1) ? Wk : Wv;
        const float* bias = (p == 0) ? bq : (p == 1) ? bk : bv;

        __syncthreads();  // prev proj's ts reads done
        // stage x slice [64 tok][64 d]
        #pragma unroll
        for (int i = 0; i < 4; ++i) {
            int idx = tid + i * 256;
            int r = idx >> 4, c4 = idx & 15;
            float4 v = *(const float4*)&x[((size_t)b * S + s0 + r) * E + h * 64 + c4 * 4];
            xs[r][c4 * 4 + 0] = v.x; xs[r][c4 * 4 + 1] = v.y;
            xs[r][c4 * 4 + 2] = v.z; xs[r][c4 * 4 + 3] = v.w;
        }
        __syncthreads();

        float acc[16];
        #pragma unroll
        for (int j = 0; j < 16; ++j) acc[j] = bias[h * 64 + w16 + j];
        #pragma unroll 4
        for (int d = 0; d < 64; ++d) {
            float xv_ = xs[lane][d];                    // broadcast-free (pad 65)
            const float* Wrow = &W[(h * 64 + d) * 64 + w16];  // uniform -> s_loads
            #pragma unroll
            for (int j = 0; j < 16; ++j) acc[j] = fmaf(xv_, Wrow[j], acc[j]);
        }
        const float scale = (p == 0) ? 0.125f : 1.0f;
        #pragma unroll
        for (int j = 0; j < 16; ++j) ts[lane][w16 + j] = acc[j] * scale;
        __syncthreads();

        if (p < 2) {
            bf16* out = (p == 0) ? Qb : Kb;
            int t = tid >> 2, eg = tid & 3;             // 4 lanes per token row
            alignas(16) bf16 tmp[16];
            #pragma unroll
            for (int i = 0; i < 16; ++i) tmp[i] = (bf16)ts[t][eg * 16 + i];
            bf16* dst = out + (bh * S + s0 + t) * 64 + eg * 16;
            *(uint4*)(dst)     = *(uint4*)&tmp[0];
            *(uint4*)(dst + 8) = *(uint4*)&tmp[8];
        } else {
            int d = tid >> 2, tg = tid & 3;             // transpose V
            alignas(16) bf16 tmp[16];
            #pragma unroll
            for (int i = 0; i < 16; ++i) tmp[i] = (bf16)ts[tg * 16 + i][d];
            bf16* dst = Vt + (bh * 64 + d) * S + s0 + tg * 16;
            *(uint4*)(dst)     = *(uint4*)&tmp[0];
            *(uint4*)(dst + 8) = *(uint4*)&tmp[8];
        }
    }
}

// ---------------------------------------------------------------------------
// Kernel 2: transpose + convert Wp (fp32 [k][n]) -> Wpt (bf16 [n][k])
// ---------------------------------------------------------------------------
__global__ __launch_bounds__(256) void prep_wp(const float* __restrict__ Wp,
                                               bf16* __restrict__ Wpt)
{
    __shared__ float t[64][65];
    const int tid = threadIdx.x;
    const int k0 = blockIdx.y * 64, n0 = blockIdx.x * 64;
    #pragma unroll
    for (int i = 0; i < 16; ++i) {
        int idx = tid + i * 256;
        int r = idx >> 6, c = idx & 63;
        t[r][c] = Wp[(size_t)(k0 + r) * E + n0 + c];
    }
    __syncthreads();
    #pragma unroll
    for (int i = 0; i < 16; ++i) {
        int idx = tid + i * 256;
        int r = idx >> 6, c = idx & 63;
        Wpt[(size_t)(n0 + r) * E + k0 + c] = (bf16)t[c][r];
    }
}

// ---------------------------------------------------------------------------
// Kernel 3: causal flash attention, bf16 MFMA 16x16x32.
// Block = 256 thr (4 waves), one (b,h) x 64-row q-tile. Wave owns 16 q rows.
// KV-tile = 32. Online softmax. ctx out: bf16 [B,S,E].
// ---------------------------------------------------------------------------
__global__ __launch_bounds__(256) void attn(
    const bf16* __restrict__ Qb, const bf16* __restrict__ Kb,
    const bf16* __restrict__ Vt, bf16* __restrict__ ctx)
{
    const int qt = blockIdx.x;       // q-tile
    const int bh = blockIdx.y;       // b*H + h
    const int b = bh >> 4, h = bh & 15;
    const int tid = threadIdx.x;
    const int w = tid >> 6, l = tid & 63;
    const int l16 = l & 15, lg = l >> 4;

    __shared__ __align__(16) bf16 Kl[32][72];     // [kv][d]  pad 72 (144B rows)
    __shared__ __align__(16) bf16 Vl[64][40];     // [d][kv]  pad 40 (80B rows)
    __shared__ __align__(16) bf16 Pl[4][16][40];  // per-wave P [q][kv]

    const bf16* Qp = Qb + (size_t)bh * S * 64;
    const bf16* Kp = Kb + (size_t)bh * S * 64;
    const bf16* Vp = Vt + (size_t)bh * 64 * S;

    const int qrow = qt * 64 + w * 16;    // wave's first q row
    // Q frags: A[i=q local][k=d], lane holds row l16, d = 8*lg+e (+32 for chunk 1)
    bf16x8 qf0 = *(const bf16x8*)(Qp + (size_t)(qrow + l16) * 64 + lg * 8);
    bf16x8 qf1 = *(const bf16x8*)(Qp + (size_t)(qrow + l16) * 64 + 32 + lg * 8);

    f32x4 o[4] = {};                     // O accum: row 4*lg+e, col d = nb*16+l16
    float m_i[4] = {-1e30f, -1e30f, -1e30f, -1e30f};
    float l_i[4] = {0.f, 0.f, 0.f, 0.f};

    const int nkt = 2 * qt + 2;
    for (int kt = 0; kt < nkt; ++kt) {
        __syncthreads();   // prev tile's LDS reads done
        {   // stage K tile [32][64] and V^T tile [64][32]
            int r = tid >> 3, c = tid & 7;
            *(uint4*)&Kl[r][c * 8] =
                *(const uint4*)(Kp + (size_t)(kt * 32 + r) * 64 + c * 8);
            int dd = tid >> 2, c2 = tid & 3;
            *(uint4*)&Vl[dd][c2 * 8] =
                *(const uint4*)(Vp + (size_t)dd * S + kt * 32 + c2 * 8);
        }
        __syncthreads();

        // QK^T: S[q][kv], two 16-kv subtiles, K-dim = 64 (2 MFMAs each)
        f32x4 sc0 = {0.f, 0.f, 0.f, 0.f}, sc1 = {0.f, 0.f, 0.f, 0.f};
        {
            bf16x8 k0a = *(const bf16x8*)&Kl[l16][lg * 8];
            bf16x8 k0b = *(const bf16x8*)&Kl[l16][32 + lg * 8];
            sc0 = __builtin_amdgcn_mfma_f32_16x16x32_bf16(qf0, k0a, sc0, 0, 0, 0);
            sc0 = __builtin_amdgcn_mfma_f32_16x16x32_bf16(qf1, k0b, sc0, 0, 0, 0);
            bf16x8 k1a = *(const bf16x8*)&Kl[16 + l16][lg * 8];
            bf16x8 k1b = *(const bf16x8*)&Kl[16 + l16][32 + lg * 8];
            sc1 = __builtin_amdgcn_mfma_f32_16x16x32_bf16(qf0, k1a, sc1, 0, 0, 0);
            sc1 = __builtin_amdgcn_mfma_f32_16x16x32_bf16(qf1, k1b, sc1, 0, 0, 0);
        }

        const bool diag = (kt >= 2 * qt);   // only last two tiles touch diagonal
        const int kvb = kt * 32;
        #pragma unroll
        for (int e = 0; e < 4; ++e) {
            const int qr = qrow + 4 * lg + e;     // absolute q of this D row
            float s0 = sc0[e], s1 = sc1[e];
            if (diag) {
                if (kvb + l16 > qr)      s0 = -1e30f;
                if (kvb + 16 + l16 > qr) s1 = -1e30f;
            }
            float mx = fmaxf(s0, s1);
            #pragma unroll
            for (int off = 1; off < 16; off <<= 1) mx = fmaxf(mx, __shfl_xor(mx, off));
            mx = fmaxf(mx, m_i[e]);
            float corr = __expf(m_i[e] - mx);
            float p0 = __expf(s0 - mx), p1 = __expf(s1 - mx);
            float rs = p0 + p1;
            #pragma unroll
            for (int off = 1; off < 16; off <<= 1) rs += __shfl_xor(rs, off);
            l_i[e] = l_i[e] * corr + rs;
            m_i[e] = mx;
            o[0][e] *= corr; o[1][e] *= corr; o[2][e] *= corr; o[3][e] *= corr;
            const int pr = 4 * lg + e;
            Pl[w][pr][l16]      = (bf16)p0;
            Pl[w][pr][16 + l16] = (bf16)p1;
        }
        // drain own-wave P writes before cross-lane read (wave-synchronous)
        asm volatile("s_waitcnt lgkmcnt(0)" ::: "memory");

        // PV: O[q][d] += P[q][kv] * V[kv][d]
        bf16x8 pf = *(const bf16x8*)&Pl[w][l16][lg * 8];
        #pragma unroll
        for (int nb = 0; nb < 4; ++nb) {
            bf16x8 vf = *(const bf16x8*)&Vl[nb * 16 + l16][lg * 8];
            o[nb] = __builtin_amdgcn_mfma_f32_16x16x32_bf16(pf, vf, o[nb], 0, 0, 0);
        }
    }

    // epilogue: normalize, write ctx [B,S,E] bf16
    #pragma unroll
    for (int e = 0; e < 4; ++e) {
        const int q = qrow + 4 * lg + e;
        const float il = 1.0f / l_i[e];
        #pragma unroll
        for (int nb = 0; nb < 4; ++nb) {
            int d = nb * 16 + l16;
            ctx[((size_t)b * S + q) * E + h * 64 + d] = (bf16)(o[nb][e] * il);
        }
    }
}

// ---------------------------------------------------------------------------
// Kernel 4: out = ctx[8192x1024] @ Wp[1024x1024] + bp, fp32 out.
// A = ctx (bf16, row-major), B = Wpt (bf16 [n][k]). 128x128 tile, BK=64,
// 4 waves (2x2), each 64x64 (4x4 16x16 frags). XOR-swizzled LDS.
// ---------------------------------------------------------------------------
__global__ __launch_bounds__(256) void out_gemm(
    const bf16* __restrict__ A, const bf16* __restrict__ Bt,
    const float* __restrict__ bp, float* __restrict__ C)
{
    const int n0 = blockIdx.x * 128, m0 = blockIdx.y * 128;
    const int tid = threadIdx.x;
    const int w = tid >> 6, l = tid & 63;
    const int l16 = l & 15, lg = l >> 4;
    const int wm = w >> 1, wn = w & 1;

    __shared__ __align__(16) bf16 Al[128][64];
    __shared__ __align__(16) bf16 Bl[128][64];

    f32x4 acc[4][4] = {};

    for (int k0 = 0; k0 < E; k0 += 64) {
        __syncthreads();
        #pragma unroll
        for (int i = 0; i < 4; ++i) {
            int row = (tid >> 3) + i * 32;
            int c = tid & 7;
            int cs = c ^ (row & 7);          // XOR swizzle 16B slots within row
            *(uint4*)&Al[row][cs * 8] =
                *(const uint4*)(A + (size_t)(m0 + row) * E + k0 + c * 8);
            *(uint4*)&Bl[row][cs * 8] =
                *(const uint4*)(Bt + (size_t)(n0 + row) * E + k0 + c * 8);
        }
        __syncthreads();

        #pragma unroll
        for (int ks = 0; ks < 2; ++ks) {
            bf16x8 af[4], bfr[4];
            #pragma unroll
            for (int mi = 0; mi < 4; ++mi) {
                int r = wm * 64 + mi * 16 + l16;
                af[mi] = *(const bf16x8*)&Al[r][((ks * 4 + lg) ^ (r & 7)) * 8];
            }
            #pragma unroll
            for (int ni = 0; ni < 4; ++ni) {
                int r = wn * 64 + ni * 16 + l16;
                bfr[ni] = *(const bf16x8*)&Bl[r][((ks * 4 + lg) ^ (r & 7)) * 8];
            }
            #pragma unroll
            for (int mi = 0; mi < 4; ++mi)
                #pragma unroll
                for (int ni = 0; ni < 4; ++ni)
                    acc[mi][ni] = __builtin_amdgcn_mfma_f32_16x16x32_bf16(
                        af[mi], bfr[ni], acc[mi][ni], 0, 0, 0);
        }
    }

    #pragma unroll
    for (int ni = 0; ni < 4; ++ni) {
        const int col = n0 + wn * 64 + ni * 16 + l16;
        const float bias = bp[col];
        #pragma unroll
        for (int mi = 0; mi < 4; ++mi) {
            #pragma unroll
            for (int e = 0; e < 4; ++e) {
                int row = m0 + wm * 64 + mi * 16 + 4 * lg + e;
                C[(size_t)row * E + col] = acc[mi][ni][e] + bias;
            }
        }
    }
}

// ---------------------------------------------------------------------------
extern "C" void kernel_launch(void* const* d_in, const int* in_sizes, int n_in,
                              void* d_out, int out_size, void* d_ws, size_t ws_size,
                              hipStream_t stream)
{
    const float* xq = (const float*)d_in[0];
    const float* xk = (const float*)d_in[1];
    const float* xv = (const float*)d_in[2];
    const float* Wq = (const float*)d_in[3];
    const float* bq = (const float*)d_in[4];
    const float* Wk = (const float*)d_in[5];
    const float* bk = (const float*)d_in[6];
    const float* Wv = (const float*)d_in[7];
    const float* bv = (const float*)d_in[8];
    const float* Wp = (const float*)d_in[9];
    const float* bp = (const float*)d_in[10];
    float* out = (float*)d_out;

    char* ws = (char*)d_ws;
    const size_t sz_bhse = (size_t)B * H * S * HD;     // 8,388,608 elems
    bf16* Qb  = (bf16*)ws;  ws += sz_bhse * 2;
    bf16* Kb  = (bf16*)ws;  ws += sz_bhse * 2;
    bf16* Vtw = (bf16*)ws;  ws += sz_bhse * 2;
    bf16* ctx = (bf16*)ws;  ws += (size_t)B * S * E * 2;
    bf16* Wpt = (bf16*)ws;  ws += (size_t)E * E * 2;   // total ~69 MB

    qkv_proj<<<dim3(S / 64, H, B), 256, 0, stream>>>(xq, xk, xv, Wq, bq, Wk, bk,
                                                     Wv, bv, Qb, Kb, Vtw);
    prep_wp<<<dim3(E / 64, E / 64), 256, 0, stream>>>(Wp, Wpt);
    attn<<<dim3(S / 64, B * H), 256, 0, stream>>>(Qb, Kb, Vtw, ctx);
    out_gemm<<<dim3(E / 128, (B * S) / 128), 256, 0, stream>>>(ctx, Wpt, bp, out);
}

// Round 3
// 173.481 us; speedup vs baseline: 2.4397x; 2.4397x over previous
//
#include <hip/hip_runtime.h>
#include <hip/hip_bf16.h>
#include <math.h>

typedef __bf16 bf16;
typedef __bf16 bf16x8 __attribute__((ext_vector_type(8)));
typedef float f32x4 __attribute__((ext_vector_type(4)));
typedef unsigned int u32x2 __attribute__((ext_vector_type(2)));

constexpr int B = 4, S = 2048, E = 1024, H = 16, HD = 64;

// 0.125 (1/sqrt(64)) * log2(e): scores in log2 domain -> raw v_exp_f32
constexpr float QSCALE = 0.125f * 1.44269504088896340736f;

static __device__ __forceinline__ float exp2_fast(float x) {
#if __has_builtin(__builtin_amdgcn_exp2f)
    return __builtin_amdgcn_exp2f(x);
#else
    float r; asm("v_exp_f32 %0, %1" : "=v"(r) : "v"(x)); return r;
#endif
}

// plain-C++ bf16 pair pack (compiler may fuse to v_cvt_pk_bf16_f32; semantics verified)
static __device__ __forceinline__ unsigned pk_bf16(float a, float b) {
    union { bf16 h[2]; unsigned u; } r;
    r.h[0] = (bf16)a; r.h[1] = (bf16)b;
    return r.u;
}

// ---------------------------------------------------------------------------
// Kernel 1: per-head QKV projections (fp32 VALU), emit bf16.
//   Q: [B,H,S,64] (pre-scaled by QSCALE)
//   K: [B,H,S,64]
//   V: [B,H,64,S]  (transposed: PV A-operand reads contiguous along kv)
// ---------------------------------------------------------------------------
__global__ __launch_bounds__(256) void qkv_proj(
    const float* __restrict__ xq, const float* __restrict__ xk, const float* __restrict__ xv,
    const float* __restrict__ Wq, const float* __restrict__ bq,
    const float* __restrict__ Wk, const float* __restrict__ bk,
    const float* __restrict__ Wv, const float* __restrict__ bv,
    bf16* __restrict__ Qb, bf16* __restrict__ Kb, bf16* __restrict__ Vt)
{
    const int b = blockIdx.z, h = blockIdx.y, s0 = blockIdx.x * 64;
    const int tid = threadIdx.x;
    const int lane = tid & 63;
    const int w16 = __builtin_amdgcn_readfirstlane((tid >> 6) * 16);

    __shared__ float xs[64][65];
    __shared__ float ts[64][65];

    const size_t bh = (size_t)b * H + h;

    for (int p = 0; p < 3; ++p) {
        const float* x    = (p == 0) ? xq : (p == 1) ? xk : xv;
        const float* W    = (p == 0) ? Wq : (p == 1) ? Wk : Wv;
        const float* bias = (p == 0) ? bq : (p == 1) ? bk : bv;

        __syncthreads();
        #pragma unroll
        for (int i = 0; i < 4; ++i) {
            int idx = tid + i * 256;
            int r = idx >> 4, c4 = idx & 15;
            float4 v = *(const float4*)&x[((size_t)b * S + s0 + r) * E + h * 64 + c4 * 4];
            xs[r][c4 * 4 + 0] = v.x; xs[r][c4 * 4 + 1] = v.y;
            xs[r][c4 * 4 + 2] = v.z; xs[r][c4 * 4 + 3] = v.w;
        }
        __syncthreads();

        float acc[16];
        #pragma unroll
        for (int j = 0; j < 16; ++j) acc[j] = bias[h * 64 + w16 + j];
        #pragma unroll 4
        for (int d = 0; d < 64; ++d) {
            float xv_ = xs[lane][d];
            const float* Wrow = &W[(h * 64 + d) * 64 + w16];
            #pragma unroll
            for (int j = 0; j < 16; ++j) acc[j] = fmaf(xv_, Wrow[j], acc[j]);
        }
        const float scale = (p == 0) ? QSCALE : 1.0f;
        #pragma unroll
        for (int j = 0; j < 16; ++j) ts[lane][w16 + j] = acc[j] * scale;
        __syncthreads();

        if (p < 2) {
            bf16* out = (p == 0) ? Qb : Kb;
            int t = tid >> 2, eg = tid & 3;
            alignas(16) bf16 tmp[16];
            #pragma unroll
            for (int i = 0; i < 16; ++i) tmp[i] = (bf16)ts[t][eg * 16 + i];
            bf16* dst = out + (bh * S + s0 + t) * 64 + eg * 16;
            *(uint4*)(dst)     = *(uint4*)&tmp[0];
            *(uint4*)(dst + 8) = *(uint4*)&tmp[8];
        } else {
            int d = tid >> 2, tg = tid & 3;
            alignas(16) bf16 tmp[16];
            #pragma unroll
            for (int i = 0; i < 16; ++i) tmp[i] = (bf16)ts[tg * 16 + i][d];
            bf16* dst = Vt + (bh * 64 + d) * S + s0 + tg * 16;
            *(uint4*)(dst)     = *(uint4*)&tmp[0];
            *(uint4*)(dst + 8) = *(uint4*)&tmp[8];
        }
    }
}

// ---------------------------------------------------------------------------
// Kernel 2: transpose + convert Wp (fp32 [k][n]) -> Wpt (bf16 [n][k])
// ---------------------------------------------------------------------------
__global__ __launch_bounds__(256) void prep_wp(const float* __restrict__ Wp,
                                               bf16* __restrict__ Wpt)
{
    __shared__ float t[64][65];
    const int tid = threadIdx.x;
    const int k0 = blockIdx.y * 64, n0 = blockIdx.x * 64;
    #pragma unroll
    for (int i = 0; i < 16; ++i) {
        int idx = tid + i * 256;
        int r = idx >> 6, c = idx & 63;
        t[r][c] = Wp[(size_t)(k0 + r) * E + n0 + c];
    }
    __syncthreads();
    #pragma unroll
    for (int i = 0; i < 16; ++i) {
        int idx = tid + i * 256;
        int r = idx >> 6, c = idx & 63;
        Wpt[(size_t)(n0 + r) * E + k0 + c] = (bf16)t[c][r];
    }
}

// ---------------------------------------------------------------------------
// Kernel 3: causal flash attention. ONLY verified primitives:
// 16x16x32 MFMA (layouts pinned by round-0 pass), __shfl_xor, LDS.
//
// 8 warps x 16 q-rows = 128-q block; KVBLK = 64; q-tile pairing (p, 15-p).
// Swapped QK^T: S^T[kv][q] = mfma(A=K, B=Q^T) -> lane owns col q = l&15,
// rows kv = 16s + 4*lg + e. Row softmax = 16 in-lane values + 2 shfl_xor.
// P routed via tiny per-warp padded LDS (4 b64 writes / 2 b128 reads).
// Swapped PV: O^T[d][q] = mfma(A=V^T, B=P^T) -> stats stay lane-local.
// ---------------------------------------------------------------------------
__global__ __launch_bounds__(512) void attn(
    const bf16* __restrict__ Qb, const bf16* __restrict__ Kb,
    const bf16* __restrict__ Vt, bf16* __restrict__ ctx)
{
    const int pair = blockIdx.x;     // 0..7
    const int bh   = blockIdx.y;     // b*H + h
    const int b = bh >> 4, h = bh & 15;
    const int tid = threadIdx.x;
    const int w = tid >> 6;          // warp 0..7
    const int l = tid & 63;
    const int l16 = l & 15, lg = l >> 4;

    __shared__ __align__(16) bf16 Kl[2][64][64];   // 16 KB (double-buffered)
    __shared__ __align__(16) bf16 Vl[2][64][64];   // 16 KB
    __shared__ __align__(16) bf16 Pl[8][16][72];   // 18 KB, stride 72 (144B rows)

    const bf16* Qp = Qb + (size_t)bh * S * 64;
    const bf16* Kp = Kb + (size_t)bh * S * 64;
    const bf16* Vp = Vt + (size_t)bh * 64 * S;

    // staging: 512 thr x 16B = one 64x64 bf16 tile per array, XOR-swizzled
    const int str = tid >> 3;                 // row 0..63
    const int stc = tid & 7;                  // 16B slot 0..7
    const int sws = (stc ^ (str & 7)) * 8;

    #pragma unroll 1
    for (int half = 0; half < 2; ++half) {
        const int qt   = half ? (15 - pair) : pair;
        const int qw0  = qt * 128 + w * 16;   // warp's first q row
        const int qabs = qw0 + l16;           // lane's q row
        const int nt   = 2 * qt + 2;          // kv tiles (always even)

        // Q frags (B-operand): lane holds Q[qabs][c*32 + lg*8 + e]
        bf16x8 qf0 = *(const bf16x8*)(Qp + (size_t)qabs * 64 + lg * 8);
        bf16x8 qf1 = *(const bf16x8*)(Qp + (size_t)qabs * 64 + 32 + lg * 8);

        f32x4 o[4] = {};                      // O^T: d = 16*ds + 4*lg + e, col q
        float m_run = -1e30f, l_run = 0.f;

        {   // prologue: stage tile 0 into buffer 0
            uint4 kreg = *(const uint4*)(Kp + (size_t)str * 64 + stc * 8);
            uint4 vreg = *(const uint4*)(Vp + (size_t)str * S + stc * 8);
            *(uint4*)&Kl[0][str][sws] = kreg;
            *(uint4*)&Vl[0][str][sws] = vreg;
        }
        int cur = 0;
        for (int t = 0; t < nt; ++t) {
            __syncthreads();                  // buf[cur] staged; buf[cur^1] free
            const bool pfv = (t + 1 < nt);
            uint4 kreg, vreg;
            if (pfv) {                        // issue-early (T14)
                const int kv1 = (t + 1) * 64;
                kreg = *(const uint4*)(Kp + (size_t)(kv1 + str) * 64 + stc * 8);
                vreg = *(const uint4*)(Vp + (size_t)str * S + kv1 + stc * 8);
            }
            const int kv0 = t * 64;
            if (kv0 < qw0 + 16) {             // warp-uniform causal skip
                // ---- QK^T (swapped): S^T[kv][q], 8 MFMAs ----
                float p[16];
                #pragma unroll
                for (int s = 0; s < 4; ++s) {
                    f32x4 sc = {0.f, 0.f, 0.f, 0.f};
                    const int row = 16 * s + l16;
                    bf16x8 ka = *(const bf16x8*)&Kl[cur][row][(lg       ^ (l16 & 7)) * 8];
                    bf16x8 kb = *(const bf16x8*)&Kl[cur][row][((4 + lg) ^ (l16 & 7)) * 8];
                    sc = __builtin_amdgcn_mfma_f32_16x16x32_bf16(ka, qf0, sc, 0, 0, 0);
                    sc = __builtin_amdgcn_mfma_f32_16x16x32_bf16(kb, qf1, sc, 0, 0, 0);
                    p[4 * s + 0] = sc[0]; p[4 * s + 1] = sc[1];
                    p[4 * s + 2] = sc[2]; p[4 * s + 3] = sc[3];
                }

                // ---- causal mask (only warp-diagonal tiles) ----
                if (kv0 + 63 > qw0) {
                    #pragma unroll
                    for (int i = 0; i < 16; ++i) {
                        const int kvloc = 16 * (i >> 2) + 4 * lg + (i & 3);
                        if (kv0 + kvloc > qabs) p[i] = -1e30f;
                    }
                }

                // ---- online softmax: in-lane 16 + 2-step shfl over lg group ----
                float mx = p[0];
                #pragma unroll
                for (int i = 1; i < 16; ++i) mx = fmaxf(mx, p[i]);
                mx = fmaxf(mx, __shfl_xor(mx, 16));
                mx = fmaxf(mx, __shfl_xor(mx, 32));
                const float m_new = fmaxf(m_run, mx);
                const float corr = exp2_fast(m_run - m_new);
                float sum = 0.f;
                #pragma unroll
                for (int i = 0; i < 16; ++i) { p[i] = exp2_fast(p[i] - m_new); sum += p[i]; }
                sum += __shfl_xor(sum, 16);
                sum += __shfl_xor(sum, 32);
                l_run = l_run * corr + sum;
                m_run = m_new;
                #pragma unroll
                for (int ds = 0; ds < 4; ++ds) {
                    o[ds][0] *= corr; o[ds][1] *= corr;
                    o[ds][2] *= corr; o[ds][3] *= corr;
                }

                // ---- P -> per-warp LDS (bf16), then read PV B-frags ----
                #pragma unroll
                for (int s = 0; s < 4; ++s) {
                    u32x2 pw;
                    pw[0] = pk_bf16(p[4 * s + 0], p[4 * s + 1]);
                    pw[1] = pk_bf16(p[4 * s + 2], p[4 * s + 3]);
                    *(u32x2*)&Pl[w][l16][16 * s + 4 * lg] = pw;   // kv = 16s+4lg..+3
                }
                asm volatile("s_waitcnt lgkmcnt(0)" ::: "memory"); // own-wave RAW
                bf16x8 pf0 = *(const bf16x8*)&Pl[w][l16][8 * lg];        // kv 8lg..+7
                bf16x8 pf1 = *(const bf16x8*)&Pl[w][l16][32 + 8 * lg];   // +32

                // ---- PV (swapped): O^T[d][q] += V^T[d][kv] P^T[kv][q], 8 MFMAs ----
                #pragma unroll
                for (int ds = 0; ds < 4; ++ds) {
                    const int row = 16 * ds + l16;
                    bf16x8 v0 = *(const bf16x8*)&Vl[cur][row][(lg       ^ (l16 & 7)) * 8];
                    bf16x8 v1 = *(const bf16x8*)&Vl[cur][row][((4 + lg) ^ (l16 & 7)) * 8];
                    o[ds] = __builtin_amdgcn_mfma_f32_16x16x32_bf16(v0, pf0, o[ds], 0, 0, 0);
                    o[ds] = __builtin_amdgcn_mfma_f32_16x16x32_bf16(v1, pf1, o[ds], 0, 0, 0);
                }
            }
            if (pfv) {                        // write-late into other buffer
                *(uint4*)&Kl[cur ^ 1][str][sws] = kreg;
                *(uint4*)&Vl[cur ^ 1][str][sws] = vreg;
            }
            cur ^= 1;
        }

        // ---- epilogue: O^T / l -> ctx[B,S,E] bf16 ----
        const float il = 1.0f / l_run;
        bf16* crow = ctx + ((size_t)b * S + qabs) * E + h * 64;
        #pragma unroll
        for (int ds = 0; ds < 4; ++ds) {
            u32x2 pw;
            pw[0] = pk_bf16(o[ds][0] * il, o[ds][1] * il);
            pw[1] = pk_bf16(o[ds][2] * il, o[ds][3] * il);
            *(u32x2*)(crow + 16 * ds + 4 * lg) = pw;
        }
        // cross-half safety: last tile reads hit buf1 (nt even); next prologue
        // writes buf0, whose last reads finished before the t=nt-1 barrier.
    }
}

// ---------------------------------------------------------------------------
// Kernel 4: out = ctx[8192x1024] @ Wp[1024x1024] + bp, fp32 out. (verified)
// ---------------------------------------------------------------------------
__global__ __launch_bounds__(256) void out_gemm(
    const bf16* __restrict__ A, const bf16* __restrict__ Bt,
    const float* __restrict__ bp, float* __restrict__ C)
{
    const int n0 = blockIdx.x * 128, m0 = blockIdx.y * 128;
    const int tid = threadIdx.x;
    const int w = tid >> 6, l = tid & 63;
    const int l16 = l & 15, lg = l >> 4;
    const int wm = w >> 1, wn = w & 1;

    __shared__ __align__(16) bf16 Al[128][64];
    __shared__ __align__(16) bf16 Bl[128][64];

    f32x4 acc[4][4] = {};

    for (int k0 = 0; k0 < E; k0 += 64) {
        __syncthreads();
        #pragma unroll
        for (int i = 0; i < 4; ++i) {
            int row = (tid >> 3) + i * 32;
            int c = tid & 7;
            int cs = c ^ (row & 7);
            *(uint4*)&Al[row][cs * 8] =
                *(const uint4*)(A + (size_t)(m0 + row) * E + k0 + c * 8);
            *(uint4*)&Bl[row][cs * 8] =
                *(const uint4*)(Bt + (size_t)(n0 + row) * E + k0 + c * 8);
        }
        __syncthreads();

        #pragma unroll
        for (int ks = 0; ks < 2; ++ks) {
            bf16x8 af[4], bfr[4];
            #pragma unroll
            for (int mi = 0; mi < 4; ++mi) {
                int r = wm * 64 + mi * 16 + l16;
                af[mi] = *(const bf16x8*)&Al[r][((ks * 4 + lg) ^ (r & 7)) * 8];
            }
            #pragma unroll
            for (int ni = 0; ni < 4; ++ni) {
                int r = wn * 64 + ni * 16 + l16;
                bfr[ni] = *(const bf16x8*)&Bl[r][((ks * 4 + lg) ^ (r & 7)) * 8];
            }
            #pragma unroll
            for (int mi = 0; mi < 4; ++mi)
                #pragma unroll
                for (int ni = 0; ni < 4; ++ni)
                    acc[mi][ni] = __builtin_amdgcn_mfma_f32_16x16x32_bf16(
                        af[mi], bfr[ni], acc[mi][ni], 0, 0, 0);
        }
    }

    #pragma unroll
    for (int ni = 0; ni < 4; ++ni) {
        const int col = n0 + wn * 64 + ni * 16 + l16;
        const float bias = bp[col];
        #pragma unroll
        for (int mi = 0; mi < 4; ++mi) {
            #pragma unroll
            for (int e = 0; e < 4; ++e) {
                int row = m0 + wm * 64 + mi * 16 + 4 * lg + e;
                C[(size_t)row * E + col] = acc[mi][ni][e] + bias;
            }
        }
    }
}

// ---------------------------------------------------------------------------
extern "C" void kernel_launch(void* const* d_in, const int* in_sizes, int n_in,
                              void* d_out, int out_size, void* d_ws, size_t ws_size,
                              hipStream_t stream)
{
    const float* xq = (const float*)d_in[0];
    const float* xk = (const float*)d_in[1];
    const float* xv = (const float*)d_in[2];
    const float* Wq = (const float*)d_in[3];
    const float* bq = (const float*)d_in[4];
    const float* Wk = (const float*)d_in[5];
    const float* bk = (const float*)d_in[6];
    const float* Wv = (const float*)d_in[7];
    const float* bv = (const float*)d_in[8];
    const float* Wp = (const float*)d_in[9];
    const float* bp = (const float*)d_in[10];
    float* out = (float*)d_out;

    char* ws = (char*)d_ws;
    const size_t sz_bhse = (size_t)B * H * S * HD;
    bf16* Qb  = (bf16*)ws;  ws += sz_bhse * 2;
    bf16* Kb  = (bf16*)ws;  ws += sz_bhse * 2;
    bf16* Vtw = (bf16*)ws;  ws += sz_bhse * 2;
    bf16* ctx = (bf16*)ws;  ws += (size_t)B * S * E * 2;
    bf16* Wpt = (bf16*)ws;  ws += (size_t)E * E * 2;

    qkv_proj<<<dim3(S / 64, H, B), 256, 0, stream>>>(xq, xk, xv, Wq, bq, Wk, bk,
                                                     Wv, bv, Qb, Kb, Vtw);
    prep_wp<<<dim3(E / 64, E / 64), 256, 0, stream>>>(Wp, Wpt);
    attn<<<dim3(8, B * H), 512, 0, stream>>>(Qb, Kb, Vtw, ctx);
    out_gemm<<<dim3(E / 128, (B * S) / 128), 256, 0, stream>>>(ctx, Wpt, bp, out);
}

// Round 4
// 132.201 us; speedup vs baseline: 3.2014x; 1.3122x over previous
//
#include <hip/hip_runtime.h>
#include <hip/hip_bf16.h>
#include <math.h>

typedef __bf16 bf16;
typedef __bf16 bf16x8 __attribute__((ext_vector_type(8)));
typedef float f32x4 __attribute__((ext_vector_type(4)));
typedef unsigned int u32x2 __attribute__((ext_vector_type(2)));

constexpr int B = 4, S = 2048, E = 1024, H = 16, HD = 64;

// 0.125 (1/sqrt(64)) * log2(e): scores in log2 domain -> raw v_exp_f32
constexpr float QSCALE = 0.125f * 1.44269504088896340736f;

static __device__ __forceinline__ float exp2_fast(float x) {
#if __has_builtin(__builtin_amdgcn_exp2f)
    return __builtin_amdgcn_exp2f(x);
#else
    float r; asm("v_exp_f32 %0, %1" : "=v"(r) : "v"(x)); return r;
#endif
}

static __device__ __forceinline__ unsigned pk_bf16(float a, float b) {
    union { bf16 h[2]; unsigned u; } r;
    r.h[0] = (bf16)a; r.h[1] = (bf16)b;
    return r.u;
}

// ---------------------------------------------------------------------------
// Kernel 0: transpose+convert per-head weights: Wq/Wk/Wv fp32 [h][d][e]
//  -> Wt bf16 [p][h][e][d]   (p=0 slice pre-scaled by QSCALE)
// ---------------------------------------------------------------------------
__global__ __launch_bounds__(256) void prep_wqkv(
    const float* __restrict__ Wq, const float* __restrict__ Wk,
    const float* __restrict__ Wv, bf16* __restrict__ Wt)
{
    const int h = blockIdx.x, p = blockIdx.y;
    const float* W = (p == 0) ? Wq : (p == 1) ? Wk : Wv;
    const float scale = (p == 0) ? QSCALE : 1.0f;
    __shared__ float t[64][65];
    const int tid = threadIdx.x;
    #pragma unroll
    for (int i = 0; i < 16; ++i) {
        int idx = tid + i * 256;
        int d = idx >> 6, e = idx & 63;
        t[d][e] = W[(size_t)h * 4096 + d * 64 + e];
    }
    __syncthreads();
    bf16* dst = Wt + ((size_t)p * H + h) * 4096;
    #pragma unroll
    for (int i = 0; i < 16; ++i) {
        int idx = tid + i * 256;
        int e = idx >> 6, d = idx & 63;
        dst[e * 64 + d] = (bf16)(t[d][e] * scale);
    }
}

// ---------------------------------------------------------------------------
// Kernel 1: QKV projections via MFMA (verified 16x16x32 contract).
// Block: 256 thr (4 waves) = 128 tokens x 1 head x all 3 projections.
//   Q/K: D[s][e] = mfma(A = x[s][k],  B = W^T[e][k])   -> [B,H,S,64]
//   V:   D[e][s] = mfma(A = W^T[e][k], B = x[s][k])    -> [B,H,64,S] (free T)
// x staged fp32->bf16 in XOR-swizzled LDS; D routed via padded LDS tile for
// vectorized global stores. Bias added in-register (Q bias scaled by QSCALE).
// ---------------------------------------------------------------------------
__global__ __launch_bounds__(256) void qkv_proj(
    const float* __restrict__ xq, const float* __restrict__ xk, const float* __restrict__ xv,
    const bf16* __restrict__ Wt,
    const float* __restrict__ bq, const float* __restrict__ bk, const float* __restrict__ bv,
    bf16* __restrict__ Qb, bf16* __restrict__ Kb, bf16* __restrict__ Vt)
{
    const int b = blockIdx.z, h = blockIdx.y, s0 = blockIdx.x * 128;
    const int tid = threadIdx.x;
    const int w = tid >> 6, l = tid & 63;
    const int l16 = l & 15, lg = l >> 4;
    const size_t bh = (size_t)b * H + h;

    __shared__ __align__(16) bf16 xs[128][64];   // 16 KB, XOR-swizzled
    __shared__ __align__(16) bf16 Wl[64][64];    //  8 KB, XOR-swizzled [e][d]
    __shared__ __align__(16) bf16 ts[10240];     // 20 KB: Q/K [128][80], V [64][136]

    for (int p = 0; p < 3; ++p) {
        const float* x    = (p == 0) ? xq : (p == 1) ? xk : xv;
        const float* bias = (p == 0) ? bq : (p == 1) ? bk : bv;
        const float  bsc  = (p == 0) ? QSCALE : 1.0f;

        __syncthreads();   // prev proj's ts-out reads + MFMA xs/Wl reads done
        // ---- stage x tile [128][64] fp32 -> bf16 swizzled ----
        #pragma unroll
        for (int i = 0; i < 4; ++i) {
            int idx = tid + i * 256;          // 0..1023 = 128 rows x 8 slots
            int r = idx >> 3, g = idx & 7;
            const float* src = &x[((size_t)b * S + s0 + r) * E + h * 64 + g * 8];
            float4 f0 = *(const float4*)src;
            float4 f1 = *(const float4*)(src + 4);
            union { bf16 h8[8]; uint4 u; } pk;
            pk.h8[0] = (bf16)f0.x; pk.h8[1] = (bf16)f0.y;
            pk.h8[2] = (bf16)f0.z; pk.h8[3] = (bf16)f0.w;
            pk.h8[4] = (bf16)f1.x; pk.h8[5] = (bf16)f1.y;
            pk.h8[6] = (bf16)f1.z; pk.h8[7] = (bf16)f1.w;
            *(uint4*)&xs[r][(g ^ (r & 7)) * 8] = pk.u;
        }
        // ---- stage W^T [64][64] bf16 swizzled ----
        const bf16* wsrc = Wt + ((size_t)p * H + h) * 4096;
        #pragma unroll
        for (int i = 0; i < 2; ++i) {
            int idx = tid + i * 256;          // 0..511 = 64 rows x 8 slots
            int e = idx >> 3, g = idx & 7;
            *(uint4*)&Wl[e][(g ^ (e & 7)) * 8] = *(const uint4*)(wsrc + e * 64 + g * 8);
        }
        __syncthreads();

        if (p < 2) {
            // ---- Q/K: wave w owns rows w*32..+31; 2x4 tiles, 16 MFMAs ----
            float bcol[4];
            #pragma unroll
            for (int ei = 0; ei < 4; ++ei)
                bcol[ei] = bias[h * 64 + ei * 16 + l16] * bsc;
            #pragma unroll
            for (int st = 0; st < 2; ++st) {
                const int srow = w * 32 + st * 16 + l16;
                bf16x8 a0 = *(const bf16x8*)&xs[srow][((lg    ) ^ (srow & 7)) * 8];
                bf16x8 a1 = *(const bf16x8*)&xs[srow][((4 + lg) ^ (srow & 7)) * 8];
                #pragma unroll
                for (int ei = 0; ei < 4; ++ei) {
                    const int erow = ei * 16 + l16;
                    bf16x8 b0 = *(const bf16x8*)&Wl[erow][((lg    ) ^ (erow & 7)) * 8];
                    bf16x8 b1 = *(const bf16x8*)&Wl[erow][((4 + lg) ^ (erow & 7)) * 8];
                    f32x4 acc = {0.f, 0.f, 0.f, 0.f};
                    acc = __builtin_amdgcn_mfma_f32_16x16x32_bf16(a0, b0, acc, 0, 0, 0);
                    acc = __builtin_amdgcn_mfma_f32_16x16x32_bf16(a1, b1, acc, 0, 0, 0);
                    #pragma unroll
                    for (int r = 0; r < 4; ++r)
                        ts[(w * 32 + st * 16 + 4 * lg + r) * 80 + ei * 16 + l16] =
                            (bf16)(acc[r] + bcol[ei]);
                }
            }
            __syncthreads();
            bf16* out = (p == 0) ? Qb : Kb;
            #pragma unroll
            for (int i = 0; i < 4; ++i) {
                int idx = tid + i * 256;
                int r = idx >> 3, g = idx & 7;
                uint4 v = *(const uint4*)&ts[r * 80 + g * 8];
                *(uint4*)(out + (bh * S + s0 + r) * 64 + g * 8) = v;
            }
        } else {
            // ---- V (swapped): wave w owns e-rows w*16..+15; 8 tiles ----
            float brow[4];
            #pragma unroll
            for (int r = 0; r < 4; ++r)
                brow[r] = bias[h * 64 + w * 16 + 4 * lg + r];
            const int erow = w * 16 + l16;
            bf16x8 a0 = *(const bf16x8*)&Wl[erow][((lg    ) ^ (erow & 7)) * 8];
            bf16x8 a1 = *(const bf16x8*)&Wl[erow][((4 + lg) ^ (erow & 7)) * 8];
            #pragma unroll
            for (int st = 0; st < 8; ++st) {
                const int srow = st * 16 + l16;
                bf16x8 b0 = *(const bf16x8*)&xs[srow][((lg    ) ^ (srow & 7)) * 8];
                bf16x8 b1 = *(const bf16x8*)&xs[srow][((4 + lg) ^ (srow & 7)) * 8];
                f32x4 acc = {0.f, 0.f, 0.f, 0.f};
                acc = __builtin_amdgcn_mfma_f32_16x16x32_bf16(a0, b0, acc, 0, 0, 0);
                acc = __builtin_amdgcn_mfma_f32_16x16x32_bf16(a1, b1, acc, 0, 0, 0);
                #pragma unroll
                for (int r = 0; r < 4; ++r)
                    ts[(w * 16 + 4 * lg + r) * 136 + st * 16 + l16] =
                        (bf16)(acc[r] + brow[r]);
            }
            __syncthreads();
            #pragma unroll
            for (int i = 0; i < 4; ++i) {
                int idx = tid + i * 256;
                int r = idx >> 4, g = idx & 15;
                uint4 v = *(const uint4*)&ts[r * 136 + g * 8];
                *(uint4*)(Vt + (bh * 64 + r) * S + s0 + g * 8) = v;
            }
        }
    }
}

// ---------------------------------------------------------------------------
// Kernel 2: transpose + convert Wp (fp32 [k][n]) -> Wpt (bf16 [n][k])
// ---------------------------------------------------------------------------
__global__ __launch_bounds__(256) void prep_wp(const float* __restrict__ Wp,
                                               bf16* __restrict__ Wpt)
{
    __shared__ float t[64][65];
    const int tid = threadIdx.x;
    const int k0 = blockIdx.y * 64, n0 = blockIdx.x * 64;
    #pragma unroll
    for (int i = 0; i < 16; ++i) {
        int idx = tid + i * 256;
        int r = idx >> 6, c = idx & 63;
        t[r][c] = Wp[(size_t)(k0 + r) * E + n0 + c];
    }
    __syncthreads();
    #pragma unroll
    for (int i = 0; i < 16; ++i) {
        int idx = tid + i * 256;
        int r = idx >> 6, c = idx & 63;
        Wpt[(size_t)(n0 + r) * E + k0 + c] = (bf16)t[c][r];
    }
}

// ---------------------------------------------------------------------------
// Kernel 3: causal flash attention (unchanged from round 3 — verified).
// ---------------------------------------------------------------------------
__global__ __launch_bounds__(512) void attn(
    const bf16* __restrict__ Qb, const bf16* __restrict__ Kb,
    const bf16* __restrict__ Vt, bf16* __restrict__ ctx)
{
    const int pair = blockIdx.x;     // 0..7
    const int bh   = blockIdx.y;     // b*H + h
    const int b = bh >> 4, h = bh & 15;
    const int tid = threadIdx.x;
    const int w = tid >> 6;          // warp 0..7
    const int l = tid & 63;
    const int l16 = l & 15, lg = l >> 4;

    __shared__ __align__(16) bf16 Kl[2][64][64];
    __shared__ __align__(16) bf16 Vl[2][64][64];
    __shared__ __align__(16) bf16 Pl[8][16][72];

    const bf16* Qp = Qb + (size_t)bh * S * 64;
    const bf16* Kp = Kb + (size_t)bh * S * 64;
    const bf16* Vp = Vt + (size_t)bh * 64 * S;

    const int str = tid >> 3;
    const int stc = tid & 7;
    const int sws = (stc ^ (str & 7)) * 8;

    #pragma unroll 1
    for (int half = 0; half < 2; ++half) {
        const int qt   = half ? (15 - pair) : pair;
        const int qw0  = qt * 128 + w * 16;
        const int qabs = qw0 + l16;
        const int nt   = 2 * qt + 2;

        bf16x8 qf0 = *(const bf16x8*)(Qp + (size_t)qabs * 64 + lg * 8);
        bf16x8 qf1 = *(const bf16x8*)(Qp + (size_t)qabs * 64 + 32 + lg * 8);

        f32x4 o[4] = {};
        float m_run = -1e30f, l_run = 0.f;

        {
            uint4 kreg = *(const uint4*)(Kp + (size_t)str * 64 + stc * 8);
            uint4 vreg = *(const uint4*)(Vp + (size_t)str * S + stc * 8);
            *(uint4*)&Kl[0][str][sws] = kreg;
            *(uint4*)&Vl[0][str][sws] = vreg;
        }
        int cur = 0;
        for (int t = 0; t < nt; ++t) {
            __syncthreads();
            const bool pfv = (t + 1 < nt);
            uint4 kreg, vreg;
            if (pfv) {
                const int kv1 = (t + 1) * 64;
                kreg = *(const uint4*)(Kp + (size_t)(kv1 + str) * 64 + stc * 8);
                vreg = *(const uint4*)(Vp + (size_t)str * S + kv1 + stc * 8);
            }
            const int kv0 = t * 64;
            if (kv0 < qw0 + 16) {
                float p[16];
                #pragma unroll
                for (int s = 0; s < 4; ++s) {
                    f32x4 sc = {0.f, 0.f, 0.f, 0.f};
                    const int row = 16 * s + l16;
                    bf16x8 ka = *(const bf16x8*)&Kl[cur][row][(lg       ^ (l16 & 7)) * 8];
                    bf16x8 kb = *(const bf16x8*)&Kl[cur][row][((4 + lg) ^ (l16 & 7)) * 8];
                    sc = __builtin_amdgcn_mfma_f32_16x16x32_bf16(ka, qf0, sc, 0, 0, 0);
                    sc = __builtin_amdgcn_mfma_f32_16x16x32_bf16(kb, qf1, sc, 0, 0, 0);
                    p[4 * s + 0] = sc[0]; p[4 * s + 1] = sc[1];
                    p[4 * s + 2] = sc[2]; p[4 * s + 3] = sc[3];
                }

                if (kv0 + 63 > qw0) {
                    #pragma unroll
                    for (int i = 0; i < 16; ++i) {
                        const int kvloc = 16 * (i >> 2) + 4 * lg + (i & 3);
                        if (kv0 + kvloc > qabs) p[i] = -1e30f;
                    }
                }

                float mx = p[0];
                #pragma unroll
                for (int i = 1; i < 16; ++i) mx = fmaxf(mx, p[i]);
                mx = fmaxf(mx, __shfl_xor(mx, 16));
                mx = fmaxf(mx, __shfl_xor(mx, 32));
                const float m_new = fmaxf(m_run, mx);
                const float corr = exp2_fast(m_run - m_new);
                float sum = 0.f;
                #pragma unroll
                for (int i = 0; i < 16; ++i) { p[i] = exp2_fast(p[i] - m_new); sum += p[i]; }
                sum += __shfl_xor(sum, 16);
                sum += __shfl_xor(sum, 32);
                l_run = l_run * corr + sum;
                m_run = m_new;
                #pragma unroll
                for (int ds = 0; ds < 4; ++ds) {
                    o[ds][0] *= corr; o[ds][1] *= corr;
                    o[ds][2] *= corr; o[ds][3] *= corr;
                }

                #pragma unroll
                for (int s = 0; s < 4; ++s) {
                    u32x2 pw;
                    pw[0] = pk_bf16(p[4 * s + 0], p[4 * s + 1]);
                    pw[1] = pk_bf16(p[4 * s + 2], p[4 * s + 3]);
                    *(u32x2*)&Pl[w][l16][16 * s + 4 * lg] = pw;
                }
                asm volatile("s_waitcnt lgkmcnt(0)" ::: "memory");
                bf16x8 pf0 = *(const bf16x8*)&Pl[w][l16][8 * lg];
                bf16x8 pf1 = *(const bf16x8*)&Pl[w][l16][32 + 8 * lg];

                #pragma unroll
                for (int ds = 0; ds < 4; ++ds) {
                    const int row = 16 * ds + l16;
                    bf16x8 v0 = *(const bf16x8*)&Vl[cur][row][(lg       ^ (l16 & 7)) * 8];
                    bf16x8 v1 = *(const bf16x8*)&Vl[cur][row][((4 + lg) ^ (l16 & 7)) * 8];
                    o[ds] = __builtin_amdgcn_mfma_f32_16x16x32_bf16(v0, pf0, o[ds], 0, 0, 0);
                    o[ds] = __builtin_amdgcn_mfma_f32_16x16x32_bf16(v1, pf1, o[ds], 0, 0, 0);
                }
            }
            if (pfv) {
                *(uint4*)&Kl[cur ^ 1][str][sws] = kreg;
                *(uint4*)&Vl[cur ^ 1][str][sws] = vreg;
            }
            cur ^= 1;
        }

        const float il = 1.0f / l_run;
        bf16* crow = ctx + ((size_t)b * S + qabs) * E + h * 64;
        #pragma unroll
        for (int ds = 0; ds < 4; ++ds) {
            u32x2 pw;
            pw[0] = pk_bf16(o[ds][0] * il, o[ds][1] * il);
            pw[1] = pk_bf16(o[ds][2] * il, o[ds][3] * il);
            *(u32x2*)(crow + 16 * ds + 4 * lg) = pw;
        }
    }
}

// ---------------------------------------------------------------------------
// Kernel 4: out = ctx[8192x1024] @ Wp[1024x1024] + bp, fp32 out. (verified)
// ---------------------------------------------------------------------------
__global__ __launch_bounds__(256) void out_gemm(
    const bf16* __restrict__ A, const bf16* __restrict__ Bt,
    const float* __restrict__ bp, float* __restrict__ C)
{
    const int n0 = blockIdx.x * 128, m0 = blockIdx.y * 128;
    const int tid = threadIdx.x;
    const int w = tid >> 6, l = tid & 63;
    const int l16 = l & 15, lg = l >> 4;
    const int wm = w >> 1, wn = w & 1;

    __shared__ __align__(16) bf16 Al[128][64];
    __shared__ __align__(16) bf16 Bl[128][64];

    f32x4 acc[4][4] = {};

    for (int k0 = 0; k0 < E; k0 += 64) {
        __syncthreads();
        #pragma unroll
        for (int i = 0; i < 4; ++i) {
            int row = (tid >> 3) + i * 32;
            int c = tid & 7;
            int cs = c ^ (row & 7);
            *(uint4*)&Al[row][cs * 8] =
                *(const uint4*)(A + (size_t)(m0 + row) * E + k0 + c * 8);
            *(uint4*)&Bl[row][cs * 8] =
                *(const uint4*)(Bt + (size_t)(n0 + row) * E + k0 + c * 8);
        }
        __syncthreads();

        #pragma unroll
        for (int ks = 0; ks < 2; ++ks) {
            bf16x8 af[4], bfr[4];
            #pragma unroll
            for (int mi = 0; mi < 4; ++mi) {
                int r = wm * 64 + mi * 16 + l16;
                af[mi] = *(const bf16x8*)&Al[r][((ks * 4 + lg) ^ (r & 7)) * 8];
            }
            #pragma unroll
            for (int ni = 0; ni < 4; ++ni) {
                int r = wn * 64 + ni * 16 + l16;
                bfr[ni] = *(const bf16x8*)&Bl[r][((ks * 4 + lg) ^ (r & 7)) * 8];
            }
            #pragma unroll
            for (int mi = 0; mi < 4; ++mi)
                #pragma unroll
                for (int ni = 0; ni < 4; ++ni)
                    acc[mi][ni] = __builtin_amdgcn_mfma_f32_16x16x32_bf16(
                        af[mi], bfr[ni], acc[mi][ni], 0, 0, 0);
        }
    }

    #pragma unroll
    for (int ni = 0; ni < 4; ++ni) {
        const int col = n0 + wn * 64 + ni * 16 + l16;
        const float bias = bp[col];
        #pragma unroll
        for (int mi = 0; mi < 4; ++mi) {
            #pragma unroll
            for (int e = 0; e < 4; ++e) {
                int row = m0 + wm * 64 + mi * 16 + 4 * lg + e;
                C[(size_t)row * E + col] = acc[mi][ni][e] + bias;
            }
        }
    }
}

// ---------------------------------------------------------------------------
extern "C" void kernel_launch(void* const* d_in, const int* in_sizes, int n_in,
                              void* d_out, int out_size, void* d_ws, size_t ws_size,
                              hipStream_t stream)
{
    const float* xq = (const float*)d_in[0];
    const float* xk = (const float*)d_in[1];
    const float* xv = (const float*)d_in[2];
    const float* Wq = (const float*)d_in[3];
    const float* bq = (const float*)d_in[4];
    const float* Wk = (const float*)d_in[5];
    const float* bk = (const float*)d_in[6];
    const float* Wv = (const float*)d_in[7];
    const float* bv = (const float*)d_in[8];
    const float* Wp = (const float*)d_in[9];
    const float* bp = (const float*)d_in[10];
    float* out = (float*)d_out;

    char* ws = (char*)d_ws;
    const size_t sz_bhse = (size_t)B * H * S * HD;
    bf16* Qb  = (bf16*)ws;  ws += sz_bhse * 2;
    bf16* Kb  = (bf16*)ws;  ws += sz_bhse * 2;
    bf16* Vtw = (bf16*)ws;  ws += sz_bhse * 2;
    bf16* ctx = (bf16*)ws;  ws += (size_t)B * S * E * 2;
    bf16* Wpt = (bf16*)ws;  ws += (size_t)E * E * 2;
    bf16* Wt3 = (bf16*)ws;  ws += (size_t)3 * H * HD * HD * 2;

    prep_wqkv<<<dim3(H, 3), 256, 0, stream>>>(Wq, Wk, Wv, Wt3);
    qkv_proj<<<dim3(S / 128, H, B), 256, 0, stream>>>(xq, xk, xv, Wt3,
                                                      bq, bk, bv, Qb, Kb, Vtw);
    prep_wp<<<dim3(E / 64, E / 64), 256, 0, stream>>>(Wp, Wpt);
    attn<<<dim3(8, B * H), 512, 0, stream>>>(Qb, Kb, Vtw, ctx);
    out_gemm<<<dim3(E / 128, (B * S) / 128), 256, 0, stream>>>(ctx, Wpt, bp, out);
}